// Round 7
// baseline (369.226 us; speedup 1.0000x reference)
//
#include <hip/hip_runtime.h>
#include <cfloat>
#include <cmath>

#define NB 2
#define NC 34
#define NH 512
#define NW 1024
#define HWSZ (NH*NW)          // 524288 = 2^19
#define TK 200
#define CAPC 49152
#define ACH 1024              // pixels per block for aggregation kernels
#define NTH 10                // "thing" classes: 24..33
#define ZWORDS (8 + NB*TK*NTH)  // ccnt(8) + segcnt

// padded layouts
#define PST 1040              // padded row stride (float4 alignment holds)
#define RPROWS 522            // reg pad: 5 top + 512 + 5 bottom
#define RPLEFT 8              // reg pad: left 8, right 8
#define VPROWS 518            // vote pad: 3 top + 512 + 3 bottom
#define VPLEFT 4              // vote pad: left 4, right 12
#define RPSZ (RPROWS*PST)
#define VPSZ (VPROWS*PST)

typedef unsigned long long u64;

// ---------------- K0: pad/zero prep (tiny) ----------------
#define PREP_ROWB (NB*2*RPROWS)            // 2088
#define PREP_BR (NB*6)                     // 12
#define PREP_ST 16                         // 4096 float4 strips / 256
#define PREP_ZB ((ZWORDS + NB*TK + 255)/256 + 1)
__global__ __launch_bounds__(256) void k_prep(const float* __restrict__ reg,
                                              float* __restrict__ reg_pad,
                                              float* __restrict__ vote_pad,
                                              int* __restrict__ zreg,
                                              float* __restrict__ o_iprob) {
    int bid = blockIdx.x;
    int tid = threadIdx.x;
    const float4 NEG4 = make_float4(-INFINITY, -INFINITY, -INFINITY, -INFINITY);
    if (bid < PREP_ROWB) {
        int bc = bid / RPROWS;
        int r = bid % RPROWS;
        float* dst = reg_pad + (size_t)bc * RPSZ + (size_t)r * PST;
        if (r >= 5 && r < 517) {
            const float* src = reg + (size_t)bc * HWSZ + (size_t)(r - 5) * NW;
            *(float4*)(dst + RPLEFT + 4 * tid) = *(const float4*)(src + 4 * tid);
            if (tid < 2) *(float4*)(dst + 4 * tid) = make_float4(0.f, 0.f, 0.f, 0.f);
            else if (tid < 4) *(float4*)(dst + 1032 + 4 * (tid - 2)) = make_float4(0.f, 0.f, 0.f, 0.f);
        } else {
            for (int i = tid; i < PST / 4; i += 256)
                *(float4*)(dst + 4 * i) = make_float4(0.f, 0.f, 0.f, 0.f);
        }
    } else if (bid < PREP_ROWB + PREP_BR) {
        int bid2 = bid - PREP_ROWB;
        int bb = bid2 / 6;
        int rsel = bid2 % 6;
        int r = (rsel < 3) ? rsel : (512 + rsel);      // 0,1,2,515,516,517
        float* dst = vote_pad + (size_t)bb * VPSZ + (size_t)r * PST;
        for (int i = tid; i < PST / 4; i += 256)
            *(float4*)(dst + 4 * i) = NEG4;
    } else if (bid < PREP_ROWB + PREP_BR + PREP_ST) {
        int idx = (bid - PREP_ROWB - PREP_BR) * 256 + tid;   // 0..4095
        int bb = idx >> 11;
        int rem = idx & 2047;
        int r = 3 + (rem >> 2);                              // 3..514
        int s = rem & 3;
        int f4 = (s == 0) ? 0 : (256 + s);                   // 0 | 257,258,259
        *(float4*)(vote_pad + (size_t)bb * VPSZ + (size_t)r * PST + 4 * f4) = NEG4;
    } else {
        int z = (bid - (PREP_ROWB + PREP_BR + PREP_ST)) * 256 + tid;
        if (z < ZWORDS) zreg[z] = 0;
        else if (z < ZWORDS + NB * TK) o_iprob[z - ZWORDS] = 0.f;
    }
}

#define GETC(f, idx) (((idx)&3)==0 ? f[(idx)>>2].x : ((idx)&3)==1 ? f[(idx)>>2].y : \
                      ((idx)&3)==2 ? f[(idx)>>2].z : f[(idx)>>2].w)

// ---------------- K1: vote blocks [0,1024) + seg blocks [1024,5120), clustered ----------------
// Clustered layout (R3-verified): consecutive vote bids keep the XCD row-swizzle's
// blk->XCD round-robin intact (L2 reg_pad locality). Seg: 1 px/thread, all 34
// logits register-resident (single HBM read); denom via __expf (feeds iprob only).
#define VOTEB (NB*NH)                      // 1024
#define SEGB  ((NB*HWSZ)/256)              // 4096 (1 px/thread)
__global__ __launch_bounds__(256, 8) void k_vote_seg(const float* __restrict__ reg_pad,
                                                     float* __restrict__ vote_pad,
                                                     const float* __restrict__ logits,
                                                     float* __restrict__ segmap_out,
                                                     float* __restrict__ mArr,
                                                     float* __restrict__ dArr) {
    int tid = threadIdx.x;
    int bid = blockIdx.x;
    if (bid >= VOTEB) {
        // ---- softmax stats: argmax, max (exact), denom via __expf ----
        int p = (bid - VOTEB) * 256 + tid;         // 0..1048575
        int b = p >> 19;
        int pix = p & (HWSZ - 1);
        const float* basep = logits + (size_t)b * NC * HWSZ + pix;
        float v[NC];
#pragma unroll
        for (int c = 0; c < NC; c++) v[c] = basep[(size_t)c * HWSZ];
        float m = -FLT_MAX; int bc = 0;
#pragma unroll
        for (int c = 0; c < NC; c++) { if (v[c] > m) { m = v[c]; bc = c; } }
        float den = 0.f;
#pragma unroll
        for (int c = 0; c < NC; c++) den += __expf(v[c] - m);
        segmap_out[p] = (float)bc;
        mArr[p] = m;
        dArr[p] = den;
        return;
    }
    int blk = bid;                                 // 0..1023
    int b = blk >> 9;
    int q = blk & 511;
    int y = ((q & 7) << 6) | (q >> 3);    // bijection: XCD-contiguous row bands
    int xb = tid << 2;
    const float* rp0 = reg_pad + (size_t)(b * 2 + 0) * RPSZ;
    const float* rp1 = reg_pad + (size_t)(b * 2 + 1) * RPSZ;
    float a0 = 0.f, a1 = 0.f, a2 = 0.f, a3 = 0.f;

    float4 fA0[5], fA1[5], fB0[5], fB1[5];

    auto loadwin = [&](int i, float4* f0, float4* f1) {
        const float* p0 = rp0 + (size_t)(y + i) * PST + xb;
        const float* p1 = rp1 + (size_t)(y + i) * PST + xb;
#pragma unroll
        for (int t = 0; t < 5; t++) f0[t] = *(const float4*)(p0 + 4 * t);
#pragma unroll
        for (int t = 0; t < 5; t++) f1[t] = *(const float4*)(p1 + 4 * t);
    };

    auto compute = [&](int i, const float4* f0, const float4* f1) {
        int d = i - 5;
        int ad = d < 0 ? -d : d;
        int w = (int)sqrtf((float)(25 - ad * ad));   // exact for {0,9,16,21,24,25}
        int lo = 5 - w, hi = 5 + w;
        float di = (float)d;
#pragma unroll
        for (int j = 0; j < 11; j++) {
            if (j < lo || j > hi) continue;
            float dj = (float)(j - 5);
            float dx, dy, ss;
            dx = __fsub_rn(dj, GETC(f0, j+3)); dy = __fsub_rn(di, GETC(f1, j+3));
            ss = __fadd_rn(__fmul_rn(dx,dx), __fmul_rn(dy,dy));
            a0 = __fadd_rn(a0, sqrtf(ss));
            dx = __fsub_rn(dj, GETC(f0, j+4)); dy = __fsub_rn(di, GETC(f1, j+4));
            ss = __fadd_rn(__fmul_rn(dx,dx), __fmul_rn(dy,dy));
            a1 = __fadd_rn(a1, sqrtf(ss));
            dx = __fsub_rn(dj, GETC(f0, j+5)); dy = __fsub_rn(di, GETC(f1, j+5));
            ss = __fadd_rn(__fmul_rn(dx,dx), __fmul_rn(dy,dy));
            a2 = __fadd_rn(a2, sqrtf(ss));
            dx = __fsub_rn(dj, GETC(f0, j+6)); dy = __fsub_rn(di, GETC(f1, j+6));
            ss = __fadd_rn(__fmul_rn(dx,dx), __fmul_rn(dy,dy));
            a3 = __fadd_rn(a3, sqrtf(ss));
        }
    };

    loadwin(0, fA0, fA1);
#pragma unroll 1
    for (int i = 0; i < 10; i += 2) {
        loadwin(i + 1, fB0, fB1);
        compute(i, fA0, fA1);
        loadwin(i + 2, fA0, fA1);
        compute(i + 1, fB0, fB1);
    }
    compute(10, fA0, fA1);

    float4 vv;
    vv.x = __fsub_rn(-__fdiv_rn(a0, 81.0f), 1.0f);
    vv.y = __fsub_rn(-__fdiv_rn(a1, 81.0f), 1.0f);
    vv.z = __fsub_rn(-__fdiv_rn(a2, 81.0f), 1.0f);
    vv.w = __fsub_rn(-__fdiv_rn(a3, 81.0f), 1.0f);
    *(float4*)(vote_pad + (size_t)b * VPSZ + (size_t)(y + 3) * PST + (xb + VPLEFT)) = vv;
}

// ---------------- K2: 7x7 max pool, XCD-swizzled, branch-free ----------------
__global__ __launch_bounds__(256) void k_pool(const float* __restrict__ vote_pad,
                                              float* __restrict__ cmap_out,
                                              u64* __restrict__ keys,
                                              int* __restrict__ ccnt,
                                              float thr_keep) {
    int tid = threadIdx.x;
    int blk = blockIdx.x;
    int b = blk >> 9;
    int q = blk & 511;
    int y = ((q & 7) << 6) | (q >> 3);
    int xb = tid << 2;
    const float* vp = vote_pad + (size_t)b * VPSZ;
    float cm[10];
#pragma unroll
    for (int t = 0; t < 10; t++) cm[t] = -INFINITY;
    float vv[4];
#pragma unroll 1
    for (int dy = -3; dy <= 3; dy++) {
        const float* row = vp + (size_t)(y + dy + 3) * PST + xb;   // real cols [xb-4, xb+8)
        float4 A = *(const float4*)(row);
        float4 Bq = *(const float4*)(row + 4);
        float4 Cq = *(const float4*)(row + 8);
        float L[12] = {A.x,A.y,A.z,A.w, Bq.x,Bq.y,Bq.z,Bq.w, Cq.x,Cq.y,Cq.z,Cq.w};
#pragma unroll
        for (int t = 0; t < 10; t++) cm[t] = fmaxf(cm[t], L[t + 1]);
        if (dy == 0) { vv[0]=L[4]; vv[1]=L[5]; vv[2]=L[6]; vv[3]=L[7]; }
    }
    int pix = y * NW + xb;
    float cmap[4];
#pragma unroll
    for (int k = 0; k < 4; k++) {
        float mx = cm[k];
#pragma unroll
        for (int u = 1; u < 7; u++) mx = fmaxf(mx, cm[k+u]);
        bool keep = (mx == vv[k]) && (vv[k] > thr_keep);
        cmap[k] = keep ? vv[k] : 0.0f;
        if (keep) {
            int pos = atomicAdd(&ccnt[b], 1);
            if (pos < CAPC) {
                unsigned u = __float_as_uint(vv[k]);
                unsigned ou = ((int)u < 0) ? ~u : (u | 0x80000000u);
                keys[(size_t)b * CAPC + pos] = ((u64)ou << 19) | (u64)(HWSZ - 1 - (pix + k));
            }
        }
    }
    *(float4*)(cmap_out + b * HWSZ + pix) = make_float4(cmap[0],cmap[1],cmap[2],cmap[3]);
}

// Descending bitonic sort of a[0..np2) in LDS. Keys unique (or 0) -> deterministic.
__device__ inline void bitonic_desc(u64* a, int np2, int tid, int T) {
    for (int k = 2; k <= np2; k <<= 1) {
        for (int j = k >> 1; j > 0; j >>= 1) {
            for (int i = tid; i < np2; i += T) {
                int ixj = i ^ j;
                if (ixj > i) {
                    u64 x = a[i], y = a[ixj];
                    bool up = ((i & k) == 0);
                    if (up ? (x < y) : (x > y)) { a[i] = y; a[ixj] = x; }
                }
            }
            __syncthreads();
        }
    }
}

// ---------------- K3: top-200 via LDS radix-select on unique 51-bit keys ----------------
__global__ __launch_bounds__(1024) void k_topk(const u64* __restrict__ keys_g,
                                               const int* __restrict__ ccnt,
                                               float* __restrict__ cxArr,
                                               float* __restrict__ cyArr,
                                               float* __restrict__ out_centers,
                                               float* __restrict__ out_topvals) {
    __shared__ int hist[2048];
    __shared__ int ssum[1024];
    __shared__ u64 sel[256];
    __shared__ int scnt;
    __shared__ int sB, sSab, scB;
    const int T = 1024;
    int b = blockIdx.x;
    int tid = threadIdx.x;
    int n = ccnt[b];
    if (n > CAPC) n = CAPC;
    const u64* Kg = keys_g + (size_t)b * CAPC;

    u64 thr;
    if (n <= TK) {
        thr = 1;   // collect every nonzero key
    } else {
        u64 prefixval = 0;
        int pbits = 0, need = TK;
        thr = 0;
        const int widths[5] = {11, 11, 11, 11, 7};
        bool done = false;
        for (int lvl = 0; lvl < 5 && !done; ++lvl) {
            int w = widths[lvl];
            int nb = 1 << w;
            int shift = 51 - pbits - w;
            for (int i = tid; i < nb; i += T) hist[i] = 0;
            __syncthreads();
            for (int i = tid; i < n; i += T) {
                u64 k = Kg[i];
                if ((k >> (51 - pbits)) == prefixval)
                    atomicAdd(&hist[(int)((k >> shift) & (u64)(nb - 1))], 1);
            }
            __syncthreads();
            int items = (nb + T - 1) / T;   // 2 for 2048 bins, else 1
            int sv = 0;
            for (int it = 0; it < items; ++it) {
                int j = tid * items + it;
                if (j < nb) sv += hist[j];
            }
            ssum[tid] = sv;
            __syncthreads();
            // inclusive suffix scan (Hillis-Steele)
            for (int off = 1; off < T; off <<= 1) {
                int v = (tid + off < T) ? ssum[tid + off] : 0;
                __syncthreads();
                ssum[tid] += v;
                __syncthreads();
            }
            int incl = ssum[tid];
            int excl = (tid + 1 < T) ? ssum[tid + 1] : 0;
            if (excl < need && need <= incl) {   // exactly one thread
                int acc = excl;
                int base2 = tid * items;
                for (int it = items - 1; it >= 0; --it) {
                    int j = base2 + it;
                    if (j >= nb) continue;
                    int h = hist[j];
                    if (acc + h >= need) { sB = j; sSab = acc; scB = h; break; }
                    acc += h;
                }
            }
            __syncthreads();
            int B = sB, Sab = sSab, cB = scB;
            int sel_total = (TK - need) + Sab;   // keys strictly above bin B overall
            if (sel_total + cB <= 256) {
                thr = ((prefixval << w) | (u64)B) << shift;
                done = true;
            } else {
                prefixval = (prefixval << w) | (u64)B;
                pbits += w;
                need = need - Sab;
            }
            __syncthreads();
        }
    }

    if (tid == 0) scnt = 0;
    if (tid < 256) sel[tid] = 0;
    __syncthreads();
    for (int i = tid; i < n; i += T) {
        u64 k = Kg[i];
        if (k >= thr && k != 0ULL) {
            int p = atomicAdd(&scnt, 1);
            if (p < 256) sel[p] = k;
        }
    }
    __syncthreads();
    bitonic_desc(sel, 256, tid, T);
    if (tid < TK) {
        u64 w = sel[tid];
        bool valid = (w != 0ULL);
        unsigned ou = (unsigned)(w >> 19);
        unsigned ub = (ou & 0x80000000u) ? (ou & 0x7FFFFFFFu) : ~ou;
        float v = __uint_as_float(ub);
        int pix = valid ? (int)(HWSZ - 1 - (int)(w & 0x7FFFFULL)) : 0x7fffffff;
        int ys = pix >> 10;
        int xs = pix & (NW - 1);
        cxArr[b * TK + tid] = valid ? (float)xs : 1e9f;
        cyArr[b * TK + tid] = valid ? (float)ys : 1e9f;
        out_centers[(b * TK + tid) * 2 + 0] = (float)ys;
        out_centers[(b * TK + tid) * 2 + 1] = (float)xs;
        out_topvals[b * TK + tid] = valid ? v : -INFINITY;
    }
}

// ---------------- K4: instance assignment, 32x32 tiles + box-bound pruning ----------
__global__ __launch_bounds__(256) void k_assign(const float* __restrict__ reg,
                                                const float* __restrict__ segmap,
                                                const float* __restrict__ cxArr,
                                                const float* __restrict__ cyArr,
                                                float* __restrict__ out_inst,
                                                int* __restrict__ segcnt) {
    __shared__ int lcnt[TK * NTH];
    __shared__ float swx[TK];
    __shared__ float swy[TK];
    __shared__ int swk[TK];
    __shared__ float sred[256];
    __shared__ int wcnt[4];
    __shared__ float sbox[4];

    int tid = threadIdx.x;
    int bid = blockIdx.x;
    int b = bid >> 9;
    int r = bid & 511;
    int ty = r >> 5, tx = r & 31;          // 16 x 32 tiles of 32x32 px
    int y0 = ty << 5, x0 = tx << 5;
    int row = tid >> 3;
    int col = (tid & 7) << 2;
    int y = y0 + row;
    int x = x0 + col;
    int pix0 = (y << 10) + x;

    for (int t = tid; t < TK * NTH; t += 256) lcnt[t] = 0;

    const float* r0 = reg + (size_t)b * 2 * HWSZ;
    const float* r1 = r0 + HWSZ;
    float4 rx = *(const float4*)(r0 + pix0);
    float4 ry = *(const float4*)(r1 + pix0);
    float px[4], py[4];
    px[0] = __fsub_rn((float)(x + 1), rx.x); py[0] = __fsub_rn((float)(y + 1), ry.x);
    px[1] = __fsub_rn((float)(x + 2), rx.y); py[1] = __fsub_rn((float)(y + 1), ry.y);
    px[2] = __fsub_rn((float)(x + 3), rx.z); py[2] = __fsub_rn((float)(y + 1), ry.z);
    px[3] = __fsub_rn((float)(x + 4), rx.w); py[3] = __fsub_rn((float)(y + 1), ry.w);

    // --- exact box of (px,py) over the tile ---
    float pxlo = fminf(fminf(px[0], px[1]), fminf(px[2], px[3]));
    float pxhi = fmaxf(fmaxf(px[0], px[1]), fmaxf(px[2], px[3]));
    float pylo = fminf(fminf(py[0], py[1]), fminf(py[2], py[3]));
    float pyhi = fmaxf(fmaxf(py[0], py[1]), fmaxf(py[2], py[3]));
#pragma unroll
    for (int off = 32; off >= 1; off >>= 1) {
        pxlo = fminf(pxlo, __shfl_xor(pxlo, off));
        pxhi = fmaxf(pxhi, __shfl_xor(pxhi, off));
        pylo = fminf(pylo, __shfl_xor(pylo, off));
        pyhi = fmaxf(pyhi, __shfl_xor(pyhi, off));
    }
    int wid = tid >> 6;
    int lane = tid & 63;
    if (lane == 0) {
        sred[wid * 4 + 0] = pxlo; sred[wid * 4 + 1] = pxhi;
        sred[wid * 4 + 2] = pylo; sred[wid * 4 + 3] = pyhi;
    }
    __syncthreads();
    if (tid == 0) {
        float a = sred[0], bq = sred[1], c = sred[2], d = sred[3];
        for (int w = 1; w < 4; w++) {
            a  = fminf(a,  sred[w * 4 + 0]);
            bq = fmaxf(bq, sred[w * 4 + 1]);
            c  = fminf(c,  sred[w * 4 + 2]);
            d  = fmaxf(d,  sred[w * 4 + 3]);
        }
        sbox[0] = a; sbox[1] = bq; sbox[2] = c; sbox[3] = d;
    }
    __syncthreads();
    float bxlo = sbox[0], bxhi = sbox[1], bylo = sbox[2], byhi = sbox[3];

    // --- per-center bounds ---
    float Lk = 0.f, Uk = INFINITY, cxv = 0.f, cyv = 0.f;
    if (tid < TK) {
        cxv = cxArr[b * TK + tid];
        cyv = cyArr[b * TK + tid];
        float dl = fmaxf(fmaxf(__fsub_rn(bxlo, cxv), __fsub_rn(cxv, bxhi)), 0.f);
        float el = fmaxf(fmaxf(__fsub_rn(bylo, cyv), __fsub_rn(cyv, byhi)), 0.f);
        float du = fmaxf(__fsub_rn(cxv, bxlo), __fsub_rn(bxhi, cxv));
        float eu = fmaxf(__fsub_rn(cyv, bylo), __fsub_rn(byhi, cyv));
        Lk = __fadd_rn(__fmul_rn(dl, dl), __fmul_rn(el, el));
        Uk = __fadd_rn(__fmul_rn(du, du), __fmul_rn(eu, eu));
    }
    sred[tid] = Uk;
    __syncthreads();
#pragma unroll
    for (int s = 128; s > 0; s >>= 1) {
        if (tid < s) sred[tid] = fminf(sred[tid], sred[tid + s]);
        __syncthreads();
    }
    float Umin = sred[0];

    // --- stable (ascending-k) compaction of survivors ---
    bool flag = (tid < TK) && (Lk <= Umin);
    u64 mask = __ballot(flag);
    int wpre = __popcll(mask & ((1ULL << lane) - 1ULL));
    if (lane == 0) wcnt[wid] = (int)__popcll(mask);
    __syncthreads();
    int base_off = 0;
#pragma unroll
    for (int w = 0; w < 4; w++) if (w < wid) base_off += wcnt[w];
    int m = wcnt[0] + wcnt[1] + wcnt[2] + wcnt[3];
    if (flag) {
        int p = base_off + wpre;
        swx[p] = cxv; swy[p] = cyv; swk[p] = tid;
    }
    __syncthreads();

    // --- exact argmin over survivors (original op sequence, strict <) ---
    float bd[4]; int bk[4];
#pragma unroll
    for (int it = 0; it < 4; it++) { bd[it] = INFINITY; bk[it] = 0; }
    for (int k2 = 0; k2 < m; k2++) {
        float cx = swx[k2];
        float cy = swy[k2];
        int kk = swk[k2];
#pragma unroll
        for (int it = 0; it < 4; it++) {
            float dx = __fsub_rn(px[it], cx);
            float dy = __fsub_rn(py[it], cy);
            float d2 = __fadd_rn(__fmul_rn(dx, dx), __fmul_rn(dy, dy));
            if (d2 < bd[it]) { bd[it] = d2; bk[it] = kk; }
        }
    }

    float4 sm = *(const float4*)(segmap + (size_t)b * HWSZ + pix0);
    float scls[4] = {sm.x, sm.y, sm.z, sm.w};
    float oi[4];
#pragma unroll
    for (int it = 0; it < 4; it++) {
        int cls = (int)scls[it];
        int thing = (cls >= 24) ? 1 : 0;
        int inst = (bk[it] + 1) * thing;
        oi[it] = (float)inst;
        if (inst) atomicAdd(&lcnt[bk[it] * NTH + (cls - 24)], 1);
    }
    *(float4*)(out_inst + (size_t)b * HWSZ + pix0) = make_float4(oi[0], oi[1], oi[2], oi[3]);
    __syncthreads();
    for (int t = tid; t < TK * NTH; t += 256) {
        int v = lcnt[t];
        if (v) atomicAdd(&segcnt[b * TK * NTH + t], v);
    }
}

// ---------------- K5: fused per-instance stats + prob sum ----------------
__global__ __launch_bounds__(256) void k_statsprob(const float* __restrict__ logits,
                                                   const float* __restrict__ inst_f,
                                                   const float* __restrict__ mArr,
                                                   const float* __restrict__ dArr,
                                                   const int* __restrict__ segcnt,
                                                   float* __restrict__ out_icls,
                                                   float* __restrict__ out_isize,
                                                   float* __restrict__ out_iprob) {
    __shared__ float lps[TK];
    __shared__ int sicls[TK];
    __shared__ float ssz[TK];
    int tid = threadIdx.x;
    int base = blockIdx.x * ACH;
    int b = base >> 19;
    if (tid < TK) {
        const int* rowp = segcnt + (size_t)(b * TK + tid) * NTH;
        int total = 0, bc = 0, bv = -1;
#pragma unroll
        for (int c = 0; c < NTH; c++) {
            int v = rowp[c];
            total += v;
            if (v > bv) { bv = v; bc = c; }
        }
        int cls = (total == 0) ? 0 : (24 + bc);
        sicls[tid] = cls;
        ssz[tid] = fmaxf((float)total, 1.0f);
        if ((blockIdx.x & 511) == 0) {
            out_icls[b * TK + tid] = (float)cls;
            out_isize[b * TK + tid] = (float)total;
        }
    }
    for (int t = tid; t < TK; t += 256) lps[t] = 0.f;
    __syncthreads();
    int p0 = base + tid * 4;
    float4 fi = *(const float4*)(inst_f + p0);
    float4 fm = *(const float4*)(mArr + p0);
    float4 fd = *(const float4*)(dArr + p0);
    float insts[4] = {fi.x, fi.y, fi.z, fi.w};
    float ms[4] = {fm.x, fm.y, fm.z, fm.w};
    float ds[4] = {fd.x, fd.y, fd.z, fd.w};
#pragma unroll
    for (int it = 0; it < 4; it++) {
        int inst = (int)insts[it];
        if (inst) {
            int p = p0 + it;
            int pix = p & (HWSZ - 1);
            int c = sicls[inst - 1];
            float xv = logits[(size_t)(b * NC + c) * HWSZ + pix];
            float pr = __fdiv_rn(__expf(__fsub_rn(xv, ms[it])), ds[it]);
            atomicAdd(&lps[inst - 1], pr);
        }
    }
    __syncthreads();
    for (int t = tid; t < TK; t += 256) {
        float s = lps[t];
        if (s != 0.f) {
            float sz = ssz[t];
            atomicAdd(&out_iprob[b * TK + t], s / sz);
        }
    }
}

// Host: replicate _circle_constants threshold exactly (NumPy pairwise sum, f32)
static float compute_thr_keep() {
    float cdm[121];
    int t = 0;
    for (int i = 0; i < 11; i++) {
        for (int j = 0; j < 11; j++) {
            float ox = (float)(j - 5), oy = (float)(i - 5);
            float cd = sqrtf(ox * ox + oy * oy);
            float cm = (cd <= 5.0f) ? 1.0f : 0.0f;
            cdm[t++] = cd * cm;
        }
    }
    float r[8];
    for (int k = 0; k < 8; k++) r[k] = cdm[k];
    int i = 8;
    for (; i < 121 - (121 % 8); i += 8)
        for (int k = 0; k < 8; k++) r[k] += cdm[i + k];
    float res = ((r[0] + r[1]) + (r[2] + r[3])) + ((r[4] + r[5]) + (r[6] + r[7]));
    for (; i < 121; i++) res += cdm[i];
    float thr = res / 81.0f;
    double kt = -(double)thr - 1.0;
    return (float)kt;
}

extern "C" void kernel_launch(void* const* d_in, const int* in_sizes, int n_in,
                              void* d_out, int out_size, void* d_ws, size_t ws_size,
                              hipStream_t stream) {
    const float* logits = (const float*)d_in[0];
    const float* reg    = (const float*)d_in[2];
    float* out = (float*)d_out;

    // output layout (all f32)
    float* o_inst    = out;                       // B*HW
    float* o_seg     = out + 1048576;             // B*HW
    float* o_centers = out + 2097152;             // B*TK*2
    float* o_topvals = out + 2097952;             // B*TK
    float* o_icls    = out + 2098352;             // B*TK
    float* o_iprob   = out + 2098752;             // B*TK
    float* o_isize   = out + 2099152;             // B*TK
    float* o_cmap    = out + 2099552;             // B*HW

    // workspace: keys (8B aligned) first, then contiguous zero-region, then rest
    u64* keys = (u64*)d_ws;                                   // NB*CAPC
    float* wsf = (float*)(keys + (size_t)NB * CAPC);
    size_t o = 0;
    int*   zreg    = (int*)(wsf + o); o += ZWORDS;            // [ccnt(8) | segcnt]
    int*   ccnt    = zreg;
    int*   segcnt  = zreg + 8;
    float* reg_pad = wsf + o; o += (size_t)NB * 2 * RPSZ;
    float* vote_pad= wsf + o; o += (size_t)NB * VPSZ;
    float* mArr    = wsf + o; o += (size_t)NB * HWSZ;
    float* dArr    = wsf + o; o += (size_t)NB * HWSZ;
    float* cxArr   = wsf + o; o += NB * TK;
    float* cyArr   = wsf + o; o += NB * TK;

    float thr_keep = compute_thr_keep();

    int gridPrep = PREP_ROWB + PREP_BR + PREP_ST + PREP_ZB;
    int gridVS = VOTEB + SEGB;         // 5120
    int gridRow = NB * NH;             // 1024
    int gridAgg = (NB * HWSZ) / ACH;   // 1024

    k_prep<<<gridPrep, 256, 0, stream>>>(reg, reg_pad, vote_pad, zreg, o_iprob);
    k_vote_seg<<<gridVS, 256, 0, stream>>>(reg_pad, vote_pad, logits, o_seg, mArr, dArr);
    k_pool<<<gridRow, 256, 0, stream>>>(vote_pad, o_cmap, keys, ccnt, thr_keep);
    k_topk<<<NB, 1024, 0, stream>>>(keys, ccnt, cxArr, cyArr, o_centers, o_topvals);
    k_assign<<<gridAgg, 256, 0, stream>>>(reg, o_seg, cxArr, cyArr, o_inst, segcnt);
    k_statsprob<<<gridAgg, 256, 0, stream>>>(logits, o_inst, mArr, dArr, segcnt, o_icls, o_isize, o_iprob);
}

// Round 8
// 341.421 us; speedup vs baseline: 1.0814x; 1.0814x over previous
//
#include <hip/hip_runtime.h>
#include <cfloat>
#include <cmath>

#define NB 2
#define NC 34
#define NH 512
#define NW 1024
#define HWSZ (NH*NW)          // 524288 = 2^19
#define TK 200
#define CAPC 49152
#define ACH 1024              // pixels per block for aggregation kernels
#define NTH 10                // "thing" classes: 24..33
#define ZWORDS (8 + NB*TK*NTH)  // ccnt(8) + segcnt

// padded layouts
#define PST 1040              // padded row stride (float4 alignment holds)
#define RPROWS 522            // reg pad: 5 top + 512 + 5 bottom
#define RPLEFT 8              // reg pad: left 8, right 8
#define VPROWS 518            // vote pad: 3 top + 512 + 3 bottom
#define VPLEFT 4              // vote pad: left 4, right 12
#define RPSZ (RPROWS*PST)
#define VPSZ (VPROWS*PST)

typedef unsigned long long u64;

// ---------------- K0: pad/zero prep (tiny) ----------------
#define PREP_ROWB (NB*2*RPROWS)            // 2088
#define PREP_BR (NB*6)                     // 12
#define PREP_ST 16                         // 4096 float4 strips / 256
#define PREP_ZB ((ZWORDS + NB*TK + 255)/256 + 1)
__global__ __launch_bounds__(256) void k_prep(const float* __restrict__ reg,
                                              float* __restrict__ reg_pad,
                                              float* __restrict__ vote_pad,
                                              int* __restrict__ zreg,
                                              float* __restrict__ o_iprob) {
    int bid = blockIdx.x;
    int tid = threadIdx.x;
    const float4 NEG4 = make_float4(-INFINITY, -INFINITY, -INFINITY, -INFINITY);
    if (bid < PREP_ROWB) {
        int bc = bid / RPROWS;
        int r = bid % RPROWS;
        float* dst = reg_pad + (size_t)bc * RPSZ + (size_t)r * PST;
        if (r >= 5 && r < 517) {
            const float* src = reg + (size_t)bc * HWSZ + (size_t)(r - 5) * NW;
            *(float4*)(dst + RPLEFT + 4 * tid) = *(const float4*)(src + 4 * tid);
            if (tid < 2) *(float4*)(dst + 4 * tid) = make_float4(0.f, 0.f, 0.f, 0.f);
            else if (tid < 4) *(float4*)(dst + 1032 + 4 * (tid - 2)) = make_float4(0.f, 0.f, 0.f, 0.f);
        } else {
            for (int i = tid; i < PST / 4; i += 256)
                *(float4*)(dst + 4 * i) = make_float4(0.f, 0.f, 0.f, 0.f);
        }
    } else if (bid < PREP_ROWB + PREP_BR) {
        int bid2 = bid - PREP_ROWB;
        int bb = bid2 / 6;
        int rsel = bid2 % 6;
        int r = (rsel < 3) ? rsel : (512 + rsel);      // 0,1,2,515,516,517
        float* dst = vote_pad + (size_t)bb * VPSZ + (size_t)r * PST;
        for (int i = tid; i < PST / 4; i += 256)
            *(float4*)(dst + 4 * i) = NEG4;
    } else if (bid < PREP_ROWB + PREP_BR + PREP_ST) {
        int idx = (bid - PREP_ROWB - PREP_BR) * 256 + tid;   // 0..4095
        int bb = idx >> 11;
        int rem = idx & 2047;
        int r = 3 + (rem >> 2);                              // 3..514
        int s = rem & 3;
        int f4 = (s == 0) ? 0 : (256 + s);                   // 0 | 257,258,259
        *(float4*)(vote_pad + (size_t)bb * VPSZ + (size_t)r * PST + 4 * f4) = NEG4;
    } else {
        int z = (bid - (PREP_ROWB + PREP_BR + PREP_ST)) * 256 + tid;
        if (z < ZWORDS) zreg[z] = 0;
        else if (z < ZWORDS + NB * TK) o_iprob[z - ZWORDS] = 0.f;
    }
}

#define GETC(f, idx) (((idx)&3)==0 ? f[(idx)>>2].x : ((idx)&3)==1 ? f[(idx)>>2].y : \
                      ((idx)&3)==2 ? f[(idx)>>2].z : f[(idx)>>2].w)

// ---------------- K1: vote blocks [0,1024) + seg blocks [1024,5120), clustered ----------------
// R3-verified structure; only delta vs R3: seg denominator uses __expf (feeds
// o_iprob only; absmax 0.00024 << threshold, verified R6/R7).
#define VOTEB (NB*NH)                      // 1024
#define SEGB  ((NB*HWSZ)/256)              // 4096 (1 px/thread)
__global__ __launch_bounds__(256, 4) void k_vote_seg(const float* __restrict__ reg_pad,
                                                     float* __restrict__ vote_pad,
                                                     const float* __restrict__ logits,
                                                     float* __restrict__ segmap_out,
                                                     float* __restrict__ mArr,
                                                     float* __restrict__ dArr) {
    int tid = threadIdx.x;
    int bid = blockIdx.x;
    if (bid >= VOTEB) {
        // ---- softmax stats: argmax, max (exact), denom via __expf ----
        int p = (bid - VOTEB) * 256 + tid;         // 0..1048575
        int b = p >> 19;
        int pix = p & (HWSZ - 1);
        const float* basep = logits + (size_t)b * NC * HWSZ + pix;
        float v[NC];
#pragma unroll
        for (int c = 0; c < NC; c++) v[c] = basep[(size_t)c * HWSZ];
        float m = -FLT_MAX; int bc = 0;
#pragma unroll
        for (int c = 0; c < NC; c++) { if (v[c] > m) { m = v[c]; bc = c; } }
        float den = 0.f;
#pragma unroll
        for (int c = 0; c < NC; c++) den += __expf(v[c] - m);
        segmap_out[p] = (float)bc;
        mArr[p] = m;
        dArr[p] = den;
        return;
    }
    int blk = bid;                                 // 0..1023
    int b = blk >> 9;
    int q = blk & 511;
    int y = ((q & 7) << 6) | (q >> 3);    // bijection: XCD-contiguous row bands
    int xb = tid << 2;
    const float* rp0 = reg_pad + (size_t)(b * 2 + 0) * RPSZ;
    const float* rp1 = reg_pad + (size_t)(b * 2 + 1) * RPSZ;
    float a0 = 0.f, a1 = 0.f, a2 = 0.f, a3 = 0.f;

    float4 fA0[5], fA1[5], fB0[5], fB1[5];

    auto loadwin = [&](int i, float4* f0, float4* f1) {
        const float* p0 = rp0 + (size_t)(y + i) * PST + xb;
        const float* p1 = rp1 + (size_t)(y + i) * PST + xb;
#pragma unroll
        for (int t = 0; t < 5; t++) f0[t] = *(const float4*)(p0 + 4 * t);
#pragma unroll
        for (int t = 0; t < 5; t++) f1[t] = *(const float4*)(p1 + 4 * t);
    };

    auto compute = [&](int i, const float4* f0, const float4* f1) {
        int d = i - 5;
        int ad = d < 0 ? -d : d;
        int w = (int)sqrtf((float)(25 - ad * ad));   // exact for {0,9,16,21,24,25}
        int lo = 5 - w, hi = 5 + w;
        float di = (float)d;
#pragma unroll
        for (int j = 0; j < 11; j++) {
            if (j < lo || j > hi) continue;
            float dj = (float)(j - 5);
            float dx, dy, ss;
            dx = __fsub_rn(dj, GETC(f0, j+3)); dy = __fsub_rn(di, GETC(f1, j+3));
            ss = __fadd_rn(__fmul_rn(dx,dx), __fmul_rn(dy,dy));
            a0 = __fadd_rn(a0, sqrtf(ss));
            dx = __fsub_rn(dj, GETC(f0, j+4)); dy = __fsub_rn(di, GETC(f1, j+4));
            ss = __fadd_rn(__fmul_rn(dx,dx), __fmul_rn(dy,dy));
            a1 = __fadd_rn(a1, sqrtf(ss));
            dx = __fsub_rn(dj, GETC(f0, j+5)); dy = __fsub_rn(di, GETC(f1, j+5));
            ss = __fadd_rn(__fmul_rn(dx,dx), __fmul_rn(dy,dy));
            a2 = __fadd_rn(a2, sqrtf(ss));
            dx = __fsub_rn(dj, GETC(f0, j+6)); dy = __fsub_rn(di, GETC(f1, j+6));
            ss = __fadd_rn(__fmul_rn(dx,dx), __fmul_rn(dy,dy));
            a3 = __fadd_rn(a3, sqrtf(ss));
        }
    };

    loadwin(0, fA0, fA1);
#pragma unroll 1
    for (int i = 0; i < 10; i += 2) {
        loadwin(i + 1, fB0, fB1);
        compute(i, fA0, fA1);
        loadwin(i + 2, fA0, fA1);
        compute(i + 1, fB0, fB1);
    }
    compute(10, fA0, fA1);

    float4 vv;
    vv.x = __fsub_rn(-__fdiv_rn(a0, 81.0f), 1.0f);
    vv.y = __fsub_rn(-__fdiv_rn(a1, 81.0f), 1.0f);
    vv.z = __fsub_rn(-__fdiv_rn(a2, 81.0f), 1.0f);
    vv.w = __fsub_rn(-__fdiv_rn(a3, 81.0f), 1.0f);
    *(float4*)(vote_pad + (size_t)b * VPSZ + (size_t)(y + 3) * PST + (xb + VPLEFT)) = vv;
}

// ---------------- K2: 7x7 max pool, XCD-swizzled, branch-free ----------------
__global__ __launch_bounds__(256) void k_pool(const float* __restrict__ vote_pad,
                                              float* __restrict__ cmap_out,
                                              u64* __restrict__ keys,
                                              int* __restrict__ ccnt,
                                              float thr_keep) {
    int tid = threadIdx.x;
    int blk = blockIdx.x;
    int b = blk >> 9;
    int q = blk & 511;
    int y = ((q & 7) << 6) | (q >> 3);
    int xb = tid << 2;
    const float* vp = vote_pad + (size_t)b * VPSZ;
    float cm[10];
#pragma unroll
    for (int t = 0; t < 10; t++) cm[t] = -INFINITY;
    float vv[4];
#pragma unroll 1
    for (int dy = -3; dy <= 3; dy++) {
        const float* row = vp + (size_t)(y + dy + 3) * PST + xb;   // real cols [xb-4, xb+8)
        float4 A = *(const float4*)(row);
        float4 Bq = *(const float4*)(row + 4);
        float4 Cq = *(const float4*)(row + 8);
        float L[12] = {A.x,A.y,A.z,A.w, Bq.x,Bq.y,Bq.z,Bq.w, Cq.x,Cq.y,Cq.z,Cq.w};
#pragma unroll
        for (int t = 0; t < 10; t++) cm[t] = fmaxf(cm[t], L[t + 1]);
        if (dy == 0) { vv[0]=L[4]; vv[1]=L[5]; vv[2]=L[6]; vv[3]=L[7]; }
    }
    int pix = y * NW + xb;
    float cmap[4];
#pragma unroll
    for (int k = 0; k < 4; k++) {
        float mx = cm[k];
#pragma unroll
        for (int u = 1; u < 7; u++) mx = fmaxf(mx, cm[k+u]);
        bool keep = (mx == vv[k]) && (vv[k] > thr_keep);
        cmap[k] = keep ? vv[k] : 0.0f;
        if (keep) {
            int pos = atomicAdd(&ccnt[b], 1);
            if (pos < CAPC) {
                unsigned u = __float_as_uint(vv[k]);
                unsigned ou = ((int)u < 0) ? ~u : (u | 0x80000000u);
                keys[(size_t)b * CAPC + pos] = ((u64)ou << 19) | (u64)(HWSZ - 1 - (pix + k));
            }
        }
    }
    *(float4*)(cmap_out + b * HWSZ + pix) = make_float4(cmap[0],cmap[1],cmap[2],cmap[3]);
}

// Descending bitonic sort of a[0..np2) in LDS. Keys unique (or 0) -> deterministic.
__device__ inline void bitonic_desc(u64* a, int np2, int tid, int T) {
    for (int k = 2; k <= np2; k <<= 1) {
        for (int j = k >> 1; j > 0; j >>= 1) {
            for (int i = tid; i < np2; i += T) {
                int ixj = i ^ j;
                if (ixj > i) {
                    u64 x = a[i], y = a[ixj];
                    bool up = ((i & k) == 0);
                    if (up ? (x < y) : (x > y)) { a[i] = y; a[ixj] = x; }
                }
            }
            __syncthreads();
        }
    }
}

// ---------------- K3: top-200 via LDS radix-select on unique 51-bit keys ----------------
__global__ __launch_bounds__(1024) void k_topk(const u64* __restrict__ keys_g,
                                               const int* __restrict__ ccnt,
                                               float* __restrict__ cxArr,
                                               float* __restrict__ cyArr,
                                               float* __restrict__ out_centers,
                                               float* __restrict__ out_topvals) {
    __shared__ int hist[2048];
    __shared__ int ssum[1024];
    __shared__ u64 sel[256];
    __shared__ int scnt;
    __shared__ int sB, sSab, scB;
    const int T = 1024;
    int b = blockIdx.x;
    int tid = threadIdx.x;
    int n = ccnt[b];
    if (n > CAPC) n = CAPC;
    const u64* Kg = keys_g + (size_t)b * CAPC;

    u64 thr;
    if (n <= TK) {
        thr = 1;   // collect every nonzero key
    } else {
        u64 prefixval = 0;
        int pbits = 0, need = TK;
        thr = 0;
        const int widths[5] = {11, 11, 11, 11, 7};
        bool done = false;
        for (int lvl = 0; lvl < 5 && !done; ++lvl) {
            int w = widths[lvl];
            int nb = 1 << w;
            int shift = 51 - pbits - w;
            for (int i = tid; i < nb; i += T) hist[i] = 0;
            __syncthreads();
            for (int i = tid; i < n; i += T) {
                u64 k = Kg[i];
                if ((k >> (51 - pbits)) == prefixval)
                    atomicAdd(&hist[(int)((k >> shift) & (u64)(nb - 1))], 1);
            }
            __syncthreads();
            int items = (nb + T - 1) / T;   // 2 for 2048 bins, else 1
            int sv = 0;
            for (int it = 0; it < items; ++it) {
                int j = tid * items + it;
                if (j < nb) sv += hist[j];
            }
            ssum[tid] = sv;
            __syncthreads();
            // inclusive suffix scan (Hillis-Steele)
            for (int off = 1; off < T; off <<= 1) {
                int v = (tid + off < T) ? ssum[tid + off] : 0;
                __syncthreads();
                ssum[tid] += v;
                __syncthreads();
            }
            int incl = ssum[tid];
            int excl = (tid + 1 < T) ? ssum[tid + 1] : 0;
            if (excl < need && need <= incl) {   // exactly one thread
                int acc = excl;
                int base2 = tid * items;
                for (int it = items - 1; it >= 0; --it) {
                    int j = base2 + it;
                    if (j >= nb) continue;
                    int h = hist[j];
                    if (acc + h >= need) { sB = j; sSab = acc; scB = h; break; }
                    acc += h;
                }
            }
            __syncthreads();
            int B = sB, Sab = sSab, cB = scB;
            int sel_total = (TK - need) + Sab;   // keys strictly above bin B overall
            if (sel_total + cB <= 256) {
                thr = ((prefixval << w) | (u64)B) << shift;
                done = true;
            } else {
                prefixval = (prefixval << w) | (u64)B;
                pbits += w;
                need = need - Sab;
            }
            __syncthreads();
        }
    }

    if (tid == 0) scnt = 0;
    if (tid < 256) sel[tid] = 0;
    __syncthreads();
    for (int i = tid; i < n; i += T) {
        u64 k = Kg[i];
        if (k >= thr && k != 0ULL) {
            int p = atomicAdd(&scnt, 1);
            if (p < 256) sel[p] = k;
        }
    }
    __syncthreads();
    bitonic_desc(sel, 256, tid, T);
    if (tid < TK) {
        u64 w = sel[tid];
        bool valid = (w != 0ULL);
        unsigned ou = (unsigned)(w >> 19);
        unsigned ub = (ou & 0x80000000u) ? (ou & 0x7FFFFFFFu) : ~ou;
        float v = __uint_as_float(ub);
        int pix = valid ? (int)(HWSZ - 1 - (int)(w & 0x7FFFFULL)) : 0x7fffffff;
        int ys = pix >> 10;
        int xs = pix & (NW - 1);
        cxArr[b * TK + tid] = valid ? (float)xs : 1e9f;
        cyArr[b * TK + tid] = valid ? (float)ys : 1e9f;
        out_centers[(b * TK + tid) * 2 + 0] = (float)ys;
        out_centers[(b * TK + tid) * 2 + 1] = (float)xs;
        out_topvals[b * TK + tid] = valid ? v : -INFINITY;
    }
}

// ---------------- K4: instance assignment, 32x32 tiles + box-bound pruning ----------
__global__ __launch_bounds__(256) void k_assign(const float* __restrict__ reg,
                                                const float* __restrict__ segmap,
                                                const float* __restrict__ cxArr,
                                                const float* __restrict__ cyArr,
                                                float* __restrict__ out_inst,
                                                int* __restrict__ segcnt) {
    __shared__ int lcnt[TK * NTH];
    __shared__ float swx[TK];
    __shared__ float swy[TK];
    __shared__ int swk[TK];
    __shared__ float sred[256];
    __shared__ int wcnt[4];
    __shared__ float sbox[4];

    int tid = threadIdx.x;
    int bid = blockIdx.x;
    int b = bid >> 9;
    int r = bid & 511;
    int ty = r >> 5, tx = r & 31;          // 16 x 32 tiles of 32x32 px
    int y0 = ty << 5, x0 = tx << 5;
    int row = tid >> 3;
    int col = (tid & 7) << 2;
    int y = y0 + row;
    int x = x0 + col;
    int pix0 = (y << 10) + x;

    for (int t = tid; t < TK * NTH; t += 256) lcnt[t] = 0;

    const float* r0 = reg + (size_t)b * 2 * HWSZ;
    const float* r1 = r0 + HWSZ;
    float4 rx = *(const float4*)(r0 + pix0);
    float4 ry = *(const float4*)(r1 + pix0);
    float px[4], py[4];
    px[0] = __fsub_rn((float)(x + 1), rx.x); py[0] = __fsub_rn((float)(y + 1), ry.x);
    px[1] = __fsub_rn((float)(x + 2), rx.y); py[1] = __fsub_rn((float)(y + 1), ry.y);
    px[2] = __fsub_rn((float)(x + 3), rx.z); py[2] = __fsub_rn((float)(y + 1), ry.z);
    px[3] = __fsub_rn((float)(x + 4), rx.w); py[3] = __fsub_rn((float)(y + 1), ry.w);

    // --- exact box of (px,py) over the tile ---
    float pxlo = fminf(fminf(px[0], px[1]), fminf(px[2], px[3]));
    float pxhi = fmaxf(fmaxf(px[0], px[1]), fmaxf(px[2], px[3]));
    float pylo = fminf(fminf(py[0], py[1]), fminf(py[2], py[3]));
    float pyhi = fmaxf(fmaxf(py[0], py[1]), fmaxf(py[2], py[3]));
#pragma unroll
    for (int off = 32; off >= 1; off >>= 1) {
        pxlo = fminf(pxlo, __shfl_xor(pxlo, off));
        pxhi = fmaxf(pxhi, __shfl_xor(pxhi, off));
        pylo = fminf(pylo, __shfl_xor(pylo, off));
        pyhi = fmaxf(pyhi, __shfl_xor(pyhi, off));
    }
    int wid = tid >> 6;
    int lane = tid & 63;
    if (lane == 0) {
        sred[wid * 4 + 0] = pxlo; sred[wid * 4 + 1] = pxhi;
        sred[wid * 4 + 2] = pylo; sred[wid * 4 + 3] = pyhi;
    }
    __syncthreads();
    if (tid == 0) {
        float a = sred[0], bq = sred[1], c = sred[2], d = sred[3];
        for (int w = 1; w < 4; w++) {
            a  = fminf(a,  sred[w * 4 + 0]);
            bq = fmaxf(bq, sred[w * 4 + 1]);
            c  = fminf(c,  sred[w * 4 + 2]);
            d  = fmaxf(d,  sred[w * 4 + 3]);
        }
        sbox[0] = a; sbox[1] = bq; sbox[2] = c; sbox[3] = d;
    }
    __syncthreads();
    float bxlo = sbox[0], bxhi = sbox[1], bylo = sbox[2], byhi = sbox[3];

    // --- per-center bounds ---
    float Lk = 0.f, Uk = INFINITY, cxv = 0.f, cyv = 0.f;
    if (tid < TK) {
        cxv = cxArr[b * TK + tid];
        cyv = cyArr[b * TK + tid];
        float dl = fmaxf(fmaxf(__fsub_rn(bxlo, cxv), __fsub_rn(cxv, bxhi)), 0.f);
        float el = fmaxf(fmaxf(__fsub_rn(bylo, cyv), __fsub_rn(cyv, byhi)), 0.f);
        float du = fmaxf(__fsub_rn(cxv, bxlo), __fsub_rn(bxhi, cxv));
        float eu = fmaxf(__fsub_rn(cyv, bylo), __fsub_rn(byhi, cyv));
        Lk = __fadd_rn(__fmul_rn(dl, dl), __fmul_rn(el, el));
        Uk = __fadd_rn(__fmul_rn(du, du), __fmul_rn(eu, eu));
    }
    sred[tid] = Uk;
    __syncthreads();
#pragma unroll
    for (int s = 128; s > 0; s >>= 1) {
        if (tid < s) sred[tid] = fminf(sred[tid], sred[tid + s]);
        __syncthreads();
    }
    float Umin = sred[0];

    // --- stable (ascending-k) compaction of survivors ---
    bool flag = (tid < TK) && (Lk <= Umin);
    u64 mask = __ballot(flag);
    int wpre = __popcll(mask & ((1ULL << lane) - 1ULL));
    if (lane == 0) wcnt[wid] = (int)__popcll(mask);
    __syncthreads();
    int base_off = 0;
#pragma unroll
    for (int w = 0; w < 4; w++) if (w < wid) base_off += wcnt[w];
    int m = wcnt[0] + wcnt[1] + wcnt[2] + wcnt[3];
    if (flag) {
        int p = base_off + wpre;
        swx[p] = cxv; swy[p] = cyv; swk[p] = tid;
    }
    __syncthreads();

    // --- exact argmin over survivors (original op sequence, strict <) ---
    float bd[4]; int bk[4];
#pragma unroll
    for (int it = 0; it < 4; it++) { bd[it] = INFINITY; bk[it] = 0; }
    for (int k2 = 0; k2 < m; k2++) {
        float cx = swx[k2];
        float cy = swy[k2];
        int kk = swk[k2];
#pragma unroll
        for (int it = 0; it < 4; it++) {
            float dx = __fsub_rn(px[it], cx);
            float dy = __fsub_rn(py[it], cy);
            float d2 = __fadd_rn(__fmul_rn(dx, dx), __fmul_rn(dy, dy));
            if (d2 < bd[it]) { bd[it] = d2; bk[it] = kk; }
        }
    }

    float4 sm = *(const float4*)(segmap + (size_t)b * HWSZ + pix0);
    float scls[4] = {sm.x, sm.y, sm.z, sm.w};
    float oi[4];
#pragma unroll
    for (int it = 0; it < 4; it++) {
        int cls = (int)scls[it];
        int thing = (cls >= 24) ? 1 : 0;
        int inst = (bk[it] + 1) * thing;
        oi[it] = (float)inst;
        if (inst) atomicAdd(&lcnt[bk[it] * NTH + (cls - 24)], 1);
    }
    *(float4*)(out_inst + (size_t)b * HWSZ + pix0) = make_float4(oi[0], oi[1], oi[2], oi[3]);
    __syncthreads();
    for (int t = tid; t < TK * NTH; t += 256) {
        int v = lcnt[t];
        if (v) atomicAdd(&segcnt[b * TK * NTH + t], v);
    }
}

// ---------------- K5: fused per-instance stats + prob sum ----------------
__global__ __launch_bounds__(256) void k_statsprob(const float* __restrict__ logits,
                                                   const float* __restrict__ inst_f,
                                                   const float* __restrict__ mArr,
                                                   const float* __restrict__ dArr,
                                                   const int* __restrict__ segcnt,
                                                   float* __restrict__ out_icls,
                                                   float* __restrict__ out_isize,
                                                   float* __restrict__ out_iprob) {
    __shared__ float lps[TK];
    __shared__ int sicls[TK];
    __shared__ float ssz[TK];
    int tid = threadIdx.x;
    int base = blockIdx.x * ACH;
    int b = base >> 19;
    if (tid < TK) {
        const int* rowp = segcnt + (size_t)(b * TK + tid) * NTH;
        int total = 0, bc = 0, bv = -1;
#pragma unroll
        for (int c = 0; c < NTH; c++) {
            int v = rowp[c];
            total += v;
            if (v > bv) { bv = v; bc = c; }
        }
        int cls = (total == 0) ? 0 : (24 + bc);
        sicls[tid] = cls;
        ssz[tid] = fmaxf((float)total, 1.0f);
        if ((blockIdx.x & 511) == 0) {
            out_icls[b * TK + tid] = (float)cls;
            out_isize[b * TK + tid] = (float)total;
        }
    }
    for (int t = tid; t < TK; t += 256) lps[t] = 0.f;
    __syncthreads();
    int p0 = base + tid * 4;
    float4 fi = *(const float4*)(inst_f + p0);
    float4 fm = *(const float4*)(mArr + p0);
    float4 fd = *(const float4*)(dArr + p0);
    float insts[4] = {fi.x, fi.y, fi.z, fi.w};
    float ms[4] = {fm.x, fm.y, fm.z, fm.w};
    float ds[4] = {fd.x, fd.y, fd.z, fd.w};
#pragma unroll
    for (int it = 0; it < 4; it++) {
        int inst = (int)insts[it];
        if (inst) {
            int p = p0 + it;
            int pix = p & (HWSZ - 1);
            int c = sicls[inst - 1];
            float xv = logits[(size_t)(b * NC + c) * HWSZ + pix];
            float pr = __fdiv_rn(__expf(__fsub_rn(xv, ms[it])), ds[it]);
            atomicAdd(&lps[inst - 1], pr);
        }
    }
    __syncthreads();
    for (int t = tid; t < TK; t += 256) {
        float s = lps[t];
        if (s != 0.f) {
            float sz = ssz[t];
            atomicAdd(&out_iprob[b * TK + t], s / sz);
        }
    }
}

// Host: replicate _circle_constants threshold exactly (NumPy pairwise sum, f32)
static float compute_thr_keep() {
    float cdm[121];
    int t = 0;
    for (int i = 0; i < 11; i++) {
        for (int j = 0; j < 11; j++) {
            float ox = (float)(j - 5), oy = (float)(i - 5);
            float cd = sqrtf(ox * ox + oy * oy);
            float cm = (cd <= 5.0f) ? 1.0f : 0.0f;
            cdm[t++] = cd * cm;
        }
    }
    float r[8];
    for (int k = 0; k < 8; k++) r[k] = cdm[k];
    int i = 8;
    for (; i < 121 - (121 % 8); i += 8)
        for (int k = 0; k < 8; k++) r[k] += cdm[i + k];
    float res = ((r[0] + r[1]) + (r[2] + r[3])) + ((r[4] + r[5]) + (r[6] + r[7]));
    for (; i < 121; i++) res += cdm[i];
    float thr = res / 81.0f;
    double kt = -(double)thr - 1.0;
    return (float)kt;
}

extern "C" void kernel_launch(void* const* d_in, const int* in_sizes, int n_in,
                              void* d_out, int out_size, void* d_ws, size_t ws_size,
                              hipStream_t stream) {
    const float* logits = (const float*)d_in[0];
    const float* reg    = (const float*)d_in[2];
    float* out = (float*)d_out;

    // output layout (all f32)
    float* o_inst    = out;                       // B*HW
    float* o_seg     = out + 1048576;             // B*HW
    float* o_centers = out + 2097152;             // B*TK*2
    float* o_topvals = out + 2097952;             // B*TK
    float* o_icls    = out + 2098352;             // B*TK
    float* o_iprob   = out + 2098752;             // B*TK
    float* o_isize   = out + 2099152;             // B*TK
    float* o_cmap    = out + 2099552;             // B*HW

    // workspace: keys (8B aligned) first, then contiguous zero-region, then rest
    u64* keys = (u64*)d_ws;                                   // NB*CAPC
    float* wsf = (float*)(keys + (size_t)NB * CAPC);
    size_t o = 0;
    int*   zreg    = (int*)(wsf + o); o += ZWORDS;            // [ccnt(8) | segcnt]
    int*   ccnt    = zreg;
    int*   segcnt  = zreg + 8;
    float* reg_pad = wsf + o; o += (size_t)NB * 2 * RPSZ;
    float* vote_pad= wsf + o; o += (size_t)NB * VPSZ;
    float* mArr    = wsf + o; o += (size_t)NB * HWSZ;
    float* dArr    = wsf + o; o += (size_t)NB * HWSZ;
    float* cxArr   = wsf + o; o += NB * TK;
    float* cyArr   = wsf + o; o += NB * TK;

    float thr_keep = compute_thr_keep();

    int gridPrep = PREP_ROWB + PREP_BR + PREP_ST + PREP_ZB;
    int gridVS = VOTEB + SEGB;         // 5120
    int gridRow = NB * NH;             // 1024
    int gridAgg = (NB * HWSZ) / ACH;   // 1024

    k_prep<<<gridPrep, 256, 0, stream>>>(reg, reg_pad, vote_pad, zreg, o_iprob);
    k_vote_seg<<<gridVS, 256, 0, stream>>>(reg_pad, vote_pad, logits, o_seg, mArr, dArr);
    k_pool<<<gridRow, 256, 0, stream>>>(vote_pad, o_cmap, keys, ccnt, thr_keep);
    k_topk<<<NB, 1024, 0, stream>>>(keys, ccnt, cxArr, cyArr, o_centers, o_topvals);
    k_assign<<<gridAgg, 256, 0, stream>>>(reg, o_seg, cxArr, cyArr, o_inst, segcnt);
    k_statsprob<<<gridAgg, 256, 0, stream>>>(logits, o_inst, mArr, dArr, segcnt, o_icls, o_isize, o_iprob);
}